// Round 1
// baseline (156.614 us; speedup 1.0000x reference)
//
#include <hip/hip_runtime.h>
#include <math.h>

#define B_ 8
#define C_ 128
#define N_ 64
#define T_ 512
#define H_ 4
#define D_ 32
#define OUT_ 128
#define E_ 256
#define EP_ 320   // E + N self-loops
#define NEG_SLOPE 0.2f
#define BN_EPS 1e-5f

// ---------------- setup: wa[c][8] = W·att, CSR of incoming edges ----------------
__global__ void setup_kernel(const float* __restrict__ W,
                             const float* __restrict__ att_src,
                             const float* __restrict__ att_dst,
                             const int* __restrict__ edge_index,
                             float* __restrict__ wa,
                             int* __restrict__ csr_off,
                             int* __restrict__ csr_src) {
  __shared__ int cnt[N_];
  __shared__ int base[N_ + 1];
  __shared__ int fill[N_];
  __shared__ int esrc[EP_], edst[EP_];
  int tid = threadIdx.x;

  for (int idx = tid; idx < C_ * 8; idx += blockDim.x) {
    int c = idx >> 3, j = idx & 7, h = j & 3;
    const float* att = (j < 4) ? att_src : att_dst;
    float s = 0.f;
    for (int d = 0; d < D_; ++d)
      s += W[(c * H_ + h) * D_ + d] * att[h * D_ + d];
    wa[idx] = s;
  }
  if (tid < N_) { cnt[tid] = 0; fill[tid] = 0; }
  __syncthreads();
  for (int e = tid; e < EP_; e += blockDim.x) {
    int s, d;
    if (e < E_) { s = edge_index[e]; d = edge_index[E_ + e]; }
    else        { s = e - E_;        d = e - E_; }
    esrc[e] = s; edst[e] = d;
    atomicAdd(&cnt[d], 1);
  }
  __syncthreads();
  if (tid == 0) {
    int acc = 0;
    for (int n = 0; n < N_; ++n) { base[n] = acc; acc += cnt[n]; }
    base[N_] = acc;
  }
  __syncthreads();
  if (tid <= N_) csr_off[tid] = base[tid];
  for (int e = tid; e < EP_; e += blockDim.x) {
    int d = edst[e];
    int pos = base[d] + atomicAdd(&fill[d], 1);
    csr_src[pos] = esrc[e];
  }
}

// ---------------- kernel A: a[b][n][j][t] = sum_c x[b][c][n][t] * wa[c][j] ------
// grid = B*N*(T/256), block = 256, lanes over t -> perfectly coalesced x reads
__global__ void proj_kernel(const float* __restrict__ x,
                            const float* __restrict__ wa,
                            float* __restrict__ a_ws) {
  __shared__ float wal[C_ * 8];
  int tid = threadIdx.x;
  for (int i = tid; i < C_ * 8; i += 256) wal[i] = wa[i];
  __syncthreads();
  int blk = blockIdx.x;
  int tb = blk & 1;
  int n  = (blk >> 1) & (N_ - 1);
  int b  = blk >> 7;
  int t = tb * 256 + tid;
  const float* xp = x + ((size_t)(b * C_) * N_ + n) * T_ + t;
  float acc[8] = {0,0,0,0,0,0,0,0};
  for (int c = 0; c < C_; ++c) {
    float v = xp[(size_t)c * (N_ * T_)];
    const float* w8 = &wal[c * 8];
#pragma unroll
    for (int j = 0; j < 8; ++j) acc[j] = fmaf(v, w8[j], acc[j]);
  }
  float* ap = a_ws + (((size_t)b * N_ + n) * 8) * T_ + t;
#pragma unroll
  for (int j = 0; j < 8; ++j) ap[(size_t)j * T_] = acc[j];
}

// ---------------- kernel B: softmax + weighted aggregation + out ----------------
// grid = B*(T/8), block = 256. Each WG owns one b and 8 consecutive t's.
__global__ void gat_kernel(const float* __restrict__ x,
                           const float* __restrict__ a_ws,
                           const float* __restrict__ W,
                           const int* __restrict__ csr_off,
                           const int* __restrict__ csr_src,
                           const float* __restrict__ bias,
                           const float* __restrict__ bn_gamma,
                           const float* __restrict__ bn_beta,
                           const float* __restrict__ bn_mean,
                           const float* __restrict__ bn_var,
                           float* __restrict__ out) {
  __shared__ float ay[4128];            // union: a[8t][64n][8j] (4096) / y[32 rows][129]
  __shared__ float w_lds[8 * 64 * 4];   // w[t][n][h]
  __shared__ int coff[N_ + 1];
  __shared__ int csrc[EP_];
  int tid = threadIdx.x;
  int b  = blockIdx.x >> 6;
  int tb = blockIdx.x & 63;
  int t0 = tb * 8;

  if (tid <= N_) coff[tid] = csr_off[tid];
  for (int i = tid; i < EP_; i += 256) csrc[i] = csr_src[i];
  for (int i = tid; i < 8 * 64 * 4; i += 256) w_lds[i] = 0.f;

  // stage 0: load a slice -> LDS  (a_ws[b][n][j][t0..t0+7])
#pragma unroll
  for (int k = 0; k < 4; ++k) {
    int idx = k * 256 + tid;            // (n, j, t4)
    int t4 = idx & 1, j = (idx >> 1) & 7, n = idx >> 4;
    const float4 v = *reinterpret_cast<const float4*>(
        a_ws + (((size_t)b * N_ + n) * 8 + j) * T_ + t0 + t4 * 4);
    int tbase = t4 * 4;
    ay[((tbase + 0) * 64 + n) * 8 + j] = v.x;
    ay[((tbase + 1) * 64 + n) * 8 + j] = v.y;
    ay[((tbase + 2) * 64 + n) * 8 + j] = v.z;
    ay[((tbase + 3) * 64 + n) * 8 + j] = v.w;
  }
  __syncthreads();

  // stage 1: per (t, dst-node) segment softmax, accumulate w[t][src][h]
  {
    int t = tid >> 5;                   // 32 threads per t
    int nd0 = (tid & 31) * 2;           // 2 dst nodes each
    const float* at = ay + t * 64 * 8;
    for (int q = 0; q < 2; ++q) {
      int nd = nd0 + q;
      int e0 = coff[nd], e1 = coff[nd + 1];
      float adst[4];
#pragma unroll
      for (int h = 0; h < 4; ++h) adst[h] = at[nd * 8 + 4 + h];
      float mx[4] = {-1e30f, -1e30f, -1e30f, -1e30f};
      for (int e = e0; e < e1; ++e) {
        int s = csrc[e];
#pragma unroll
        for (int h = 0; h < 4; ++h) {
          float v = at[s * 8 + h] + adst[h];
          v = (v > 0.f) ? v : NEG_SLOPE * v;
          mx[h] = fmaxf(mx[h], v);
        }
      }
      float den[4] = {0, 0, 0, 0};
      for (int e = e0; e < e1; ++e) {
        int s = csrc[e];
#pragma unroll
        for (int h = 0; h < 4; ++h) {
          float v = at[s * 8 + h] + adst[h];
          v = (v > 0.f) ? v : NEG_SLOPE * v;
          den[h] += __expf(v - mx[h]);
        }
      }
#pragma unroll
      for (int h = 0; h < 4; ++h) den[h] = 1.f / (den[h] * (float)N_); // fold mean 1/N
      for (int e = e0; e < e1; ++e) {
        int s = csrc[e];
#pragma unroll
        for (int h = 0; h < 4; ++h) {
          float v = at[s * 8 + h] + adst[h];
          v = (v > 0.f) ? v : NEG_SLOPE * v;
          float alpha = __expf(v - mx[h]) * den[h];
          atomicAdd(&w_lds[(t * 64 + s) * 4 + h], alpha);
        }
      }
    }
  }
  __syncthreads();

  // stage 2: y[t][h][c] = sum_n w[t][n][h] * x[b][c][n][t0+t]   (x re-read, L3-warm)
  {
    int t = tid & 7;
    int cc = tid >> 3;                  // c in {cc*4 .. cc*4+3}
    const float* xp = x + ((size_t)b * C_ * N_) * T_ + t0 + t;
    float yr[4][4];
#pragma unroll
    for (int k = 0; k < 4; ++k)
#pragma unroll
      for (int h = 0; h < 4; ++h) yr[k][h] = 0.f;
    for (int n = 0; n < 64; ++n) {
      float4 wv = *reinterpret_cast<const float4*>(&w_lds[(t * 64 + n) * 4]);
#pragma unroll
      for (int k = 0; k < 4; ++k) {
        int c = cc * 4 + k;
        float xv = xp[((size_t)c * N_ + n) * T_];
        yr[k][0] = fmaf(xv, wv.x, yr[k][0]);
        yr[k][1] = fmaf(xv, wv.y, yr[k][1]);
        yr[k][2] = fmaf(xv, wv.z, yr[k][2]);
        yr[k][3] = fmaf(xv, wv.w, yr[k][3]);
      }
    }
    // ay no longer needed as 'a' (all stage-1 readers passed the barrier)
#pragma unroll
    for (int k = 0; k < 4; ++k)
#pragma unroll
      for (int h = 0; h < 4; ++h)
        ay[(t * 4 + h) * 129 + cc * 4 + k] = yr[k][h];
  }
  __syncthreads();

  // stage 3: out[t][h][d] = sum_c y[t][h][c] * W[c][h][d]; bias + BN; store
  {
    int t = tid & 7;
    int h = (tid >> 3) & 3;
    int dq = tid >> 5;                  // d in {dq*4 .. dq*4+3}
    float acc[4] = {0, 0, 0, 0};
    const float* yrow = ay + (t * 4 + h) * 129;
    for (int c = 0; c < C_; ++c) {
      float yv = yrow[c];
      const float4 wv = *reinterpret_cast<const float4*>(
          &W[((size_t)c * H_ + h) * D_ + dq * 4]);
      acc[0] = fmaf(yv, wv.x, acc[0]);
      acc[1] = fmaf(yv, wv.y, acc[1]);
      acc[2] = fmaf(yv, wv.z, acc[2]);
      acc[3] = fmaf(yv, wv.w, acc[3]);
    }
#pragma unroll
    for (int k = 0; k < 4; ++k) {
      int d = dq * 4 + k;
      int oc = h * D_ + d;
      float scale = bn_gamma[oc] * rsqrtf(bn_var[oc] + BN_EPS);
      float shift = bn_beta[oc] - bn_mean[oc] * scale;
      float g = acc[k] + bias[oc];
      out[((size_t)b * OUT_ + oc) * T_ + t0 + t] = g * scale + shift;
    }
  }
}

extern "C" void kernel_launch(void* const* d_in, const int* in_sizes, int n_in,
                              void* d_out, int out_size, void* d_ws, size_t ws_size,
                              hipStream_t stream) {
  const float* x        = (const float*)d_in[0];
  const float* W        = (const float*)d_in[1];
  const float* att_src  = (const float*)d_in[2];
  const float* att_dst  = (const float*)d_in[3];
  const float* bias     = (const float*)d_in[4];
  const float* bn_gamma = (const float*)d_in[5];
  const float* bn_beta  = (const float*)d_in[6];
  const float* bn_mean  = (const float*)d_in[7];
  const float* bn_var   = (const float*)d_in[8];
  const int* edge_index = (const int*)d_in[9];
  float* out = (float*)d_out;

  char* ws = (char*)d_ws;
  float* wa    = (float*)ws;                 // 1024 floats
  int* csr_off = (int*)(ws + 4096);          // 65 ints
  int* csr_src = (int*)(ws + 4608);          // 320 ints
  float* a_ws  = (float*)(ws + 8192);        // B*N*8*T floats = 8 MB

  setup_kernel<<<1, 256, 0, stream>>>(W, att_src, att_dst, edge_index,
                                      wa, csr_off, csr_src);
  proj_kernel<<<B_ * N_ * (T_ / 256), 256, 0, stream>>>(x, wa, a_ws);
  gat_kernel<<<B_ * (T_ / 8), 256, 0, stream>>>(x, a_ws, W, csr_off, csr_src,
                                                bias, bn_gamma, bn_beta,
                                                bn_mean, bn_var, out);
}

// Round 2
// 115.336 us; speedup vs baseline: 1.3579x; 1.3579x over previous
//
#include <hip/hip_runtime.h>
#include <math.h>

#define B_ 8
#define C_ 128
#define N_ 64
#define T_ 512
#define H_ 4
#define D_ 32
#define OUT_ 128
#define E_ 256
#define EP_ 320   // E + N self-loops
#define NEG_SLOPE 0.2f
#define BN_EPS 1e-5f

// ---------------- setup: wa[c][8] = W·att, CSR of incoming edges ----------------
__global__ void setup_kernel(const float* __restrict__ W,
                             const float* __restrict__ att_src,
                             const float* __restrict__ att_dst,
                             const int* __restrict__ edge_index,
                             float* __restrict__ wa,
                             int* __restrict__ csr_off,
                             int* __restrict__ csr_src) {
  __shared__ int cnt[N_];
  __shared__ int base[N_ + 1];
  __shared__ int fill[N_];
  __shared__ int esrc[EP_], edst[EP_];
  int tid = threadIdx.x;

  for (int idx = tid; idx < C_ * 8; idx += blockDim.x) {
    int c = idx >> 3, j = idx & 7, h = j & 3;
    const float* att = (j < 4) ? att_src : att_dst;
    float s = 0.f;
    for (int d = 0; d < D_; ++d)
      s += W[(c * H_ + h) * D_ + d] * att[h * D_ + d];
    wa[idx] = s;
  }
  if (tid < N_) { cnt[tid] = 0; fill[tid] = 0; }
  __syncthreads();
  for (int e = tid; e < EP_; e += blockDim.x) {
    int s, d;
    if (e < E_) { s = edge_index[e]; d = edge_index[E_ + e]; }
    else        { s = e - E_;        d = e - E_; }
    esrc[e] = s; edst[e] = d;
    atomicAdd(&cnt[d], 1);
  }
  __syncthreads();
  if (tid == 0) {
    int acc = 0;
    for (int n = 0; n < N_; ++n) { base[n] = acc; acc += cnt[n]; }
    base[N_] = acc;
  }
  __syncthreads();
  if (tid <= N_) csr_off[tid] = base[tid];
  for (int e = tid; e < EP_; e += blockDim.x) {
    int d = edst[e];
    int pos = base[d] + atomicAdd(&fill[d], 1);
    csr_src[pos] = esrc[e];
  }
}

// ---------------- kernel A: a[b][n][j][t] = sum_c x[b][c][n][t] * wa[c][j] ------
// grid = B*N*(T/256) = 1024, block = 256, lanes over t -> coalesced x reads
__global__ void proj_kernel(const float* __restrict__ x,
                            const float* __restrict__ wa,
                            float* __restrict__ a_ws) {
  __shared__ float wal[C_ * 8];
  int tid = threadIdx.x;
  for (int i = tid; i < C_ * 8; i += 256) wal[i] = wa[i];
  __syncthreads();
  int blk = blockIdx.x;
  int tb = blk & 1;
  int n  = (blk >> 1) & (N_ - 1);
  int b  = blk >> 7;
  int t = tb * 256 + tid;
  const float* xp = x + ((size_t)(b * C_) * N_ + n) * T_ + t;
  float acc[8] = {0,0,0,0,0,0,0,0};
  for (int c = 0; c < C_; ++c) {
    float v = xp[(size_t)c * (N_ * T_)];
    const float* w8 = &wal[c * 8];
#pragma unroll
    for (int j = 0; j < 8; ++j) acc[j] = fmaf(v, w8[j], acc[j]);
  }
  float* ap = a_ws + (((size_t)b * N_ + n) * 8) * T_ + t;
#pragma unroll
  for (int j = 0; j < 8; ++j) ap[(size_t)j * T_] = acc[j];
}

// ---------------- kernel B1: segment softmax -> w[b][n][t][h] -------------------
// grid = B*(T/16) = 256, block = 256 (16 threads per t, 4 dst nodes each)
__global__ void weights_kernel(const float* __restrict__ a_ws,
                               const int* __restrict__ csr_off,
                               const int* __restrict__ csr_src,
                               float* __restrict__ w_ws) {
  __shared__ float a_l[8][64][16];      // [j][n][t]  32 KB
  __shared__ float w_l[N_ * 16 * 4];    // [n][t][h]  16 KB
  __shared__ int coff[N_ + 1];
  __shared__ int csrc[EP_];
  int tid = threadIdx.x;
  int b  = blockIdx.x >> 5;
  int t0 = (blockIdx.x & 31) * 16;

  if (tid <= N_) coff[tid] = csr_off[tid];
  for (int i = tid; i < EP_; i += 256) csrc[i] = csr_src[i];
  for (int r = tid; r < 512; r += 256) {       // 512 rows of 16 floats
    int n = r >> 3, j = r & 7;
    const float4* src = reinterpret_cast<const float4*>(
        a_ws + (((size_t)b * N_ + n) * 8 + j) * T_ + t0);
    float4* dst = reinterpret_cast<float4*>(&a_l[j][n][0]);
    dst[0] = src[0]; dst[1] = src[1]; dst[2] = src[2]; dst[3] = src[3];
  }
  for (int i = tid; i < N_ * 16 * 4; i += 256) w_l[i] = 0.f;
  __syncthreads();

  int t = tid & 15, g = tid >> 4;
  for (int q = 0; q < 4; ++q) {
    int nd = g * 4 + q;
    int e0 = coff[nd], e1 = coff[nd + 1];
    float ad0 = a_l[4][nd][t], ad1 = a_l[5][nd][t];
    float ad2 = a_l[6][nd][t], ad3 = a_l[7][nd][t];
    float m0 = -1e30f, m1 = -1e30f, m2 = -1e30f, m3 = -1e30f;
    for (int e = e0; e < e1; ++e) {
      int s = csrc[e];
      float v0 = a_l[0][s][t] + ad0; v0 = v0 > 0.f ? v0 : NEG_SLOPE * v0;
      float v1 = a_l[1][s][t] + ad1; v1 = v1 > 0.f ? v1 : NEG_SLOPE * v1;
      float v2 = a_l[2][s][t] + ad2; v2 = v2 > 0.f ? v2 : NEG_SLOPE * v2;
      float v3 = a_l[3][s][t] + ad3; v3 = v3 > 0.f ? v3 : NEG_SLOPE * v3;
      m0 = fmaxf(m0, v0); m1 = fmaxf(m1, v1);
      m2 = fmaxf(m2, v2); m3 = fmaxf(m3, v3);
    }
    float d0 = 0.f, d1 = 0.f, d2 = 0.f, d3 = 0.f;
    for (int e = e0; e < e1; ++e) {
      int s = csrc[e];
      float v0 = a_l[0][s][t] + ad0; v0 = v0 > 0.f ? v0 : NEG_SLOPE * v0;
      float v1 = a_l[1][s][t] + ad1; v1 = v1 > 0.f ? v1 : NEG_SLOPE * v1;
      float v2 = a_l[2][s][t] + ad2; v2 = v2 > 0.f ? v2 : NEG_SLOPE * v2;
      float v3 = a_l[3][s][t] + ad3; v3 = v3 > 0.f ? v3 : NEG_SLOPE * v3;
      d0 += __expf(v0 - m0); d1 += __expf(v1 - m1);
      d2 += __expf(v2 - m2); d3 += __expf(v3 - m3);
    }
    float i0 = 1.f / (d0 * (float)N_);   // fold mean-over-nodes 1/N
    float i1 = 1.f / (d1 * (float)N_);
    float i2 = 1.f / (d2 * (float)N_);
    float i3 = 1.f / (d3 * (float)N_);
    for (int e = e0; e < e1; ++e) {
      int s = csrc[e];
      float v0 = a_l[0][s][t] + ad0; v0 = v0 > 0.f ? v0 : NEG_SLOPE * v0;
      float v1 = a_l[1][s][t] + ad1; v1 = v1 > 0.f ? v1 : NEG_SLOPE * v1;
      float v2 = a_l[2][s][t] + ad2; v2 = v2 > 0.f ? v2 : NEG_SLOPE * v2;
      float v3 = a_l[3][s][t] + ad3; v3 = v3 > 0.f ? v3 : NEG_SLOPE * v3;
      float* wp = &w_l[(s * 16 + t) * 4];
      atomicAdd(wp + 0, __expf(v0 - m0) * i0);
      atomicAdd(wp + 1, __expf(v1 - m1) * i1);
      atomicAdd(wp + 2, __expf(v2 - m2) * i2);
      atomicAdd(wp + 3, __expf(v3 - m3) * i3);
    }
  }
  __syncthreads();

  const float4* wl4 = reinterpret_cast<const float4*>(w_l);
  for (int i = tid; i < 1024; i += 256) {
    int n = i >> 4;
    int off = (i & 15) * 4;
    *reinterpret_cast<float4*>(
        w_ws + ((size_t)(b * N_ + n) * T_ + t0) * 4 + off) = wl4[i];
  }
}

// ---------------- kernel B2: y[b][h][c][t] = sum_n w[b][n][t][h] * x[b][c][n][t]
// grid = 1024 (XCD-swizzled (b,tc) groups x 32 c-quads), block = 256
__global__ void agg_kernel(const float* __restrict__ x,
                           const float* __restrict__ w_ws,
                           float* __restrict__ y_ws) {
  int blk = blockIdx.x;
  int xcd = blk & 7;
  int rest = blk >> 3;
  int m = rest & 31;            // c-quad
  int gq = rest >> 5;           // 0..3
  int grp = gq * 8 + xcd;       // 0..31 = (b, tc): same group -> same XCD L2
  int b = grp >> 2;
  int tc = grp & 3;
  int tid = threadIdx.x;
  int t = tc * 128 + (tid & 127);
  int c0 = m * 4 + (tid >> 7) * 2;

  const float4* wp = reinterpret_cast<const float4*>(w_ws)
                   + (size_t)b * N_ * T_ + t;
  const float* xp0 = x + (((size_t)b * C_ + c0) * N_) * T_ + t;
  const float* xp1 = xp0 + (size_t)N_ * T_;
  float y00 = 0.f, y01 = 0.f, y02 = 0.f, y03 = 0.f;
  float y10 = 0.f, y11 = 0.f, y12 = 0.f, y13 = 0.f;
#pragma unroll 4
  for (int n = 0; n < N_; ++n) {
    float4 wv = wp[(size_t)n * T_];
    float x0 = xp0[(size_t)n * T_];
    float x1 = xp1[(size_t)n * T_];
    y00 = fmaf(x0, wv.x, y00); y01 = fmaf(x0, wv.y, y01);
    y02 = fmaf(x0, wv.z, y02); y03 = fmaf(x0, wv.w, y03);
    y10 = fmaf(x1, wv.x, y10); y11 = fmaf(x1, wv.y, y11);
    y12 = fmaf(x1, wv.z, y12); y13 = fmaf(x1, wv.w, y13);
  }
  size_t yb = ((size_t)b * H_ * C_ + c0) * T_ + t;
  const size_t hs = (size_t)C_ * T_;
  y_ws[yb]              = y00; y_ws[yb + hs]     = y01;
  y_ws[yb + 2 * hs]     = y02; y_ws[yb + 3 * hs] = y03;
  y_ws[yb + T_]          = y10; y_ws[yb + hs + T_]     = y11;
  y_ws[yb + 2 * hs + T_] = y12; y_ws[yb + 3 * hs + T_] = y13;
}

// ---------------- kernel B3: out = BN(y·W + bias) -------------------------------
// grid = B*H*(T/64) = 256, block = 256
__global__ void out_kernel(const float* __restrict__ y_ws,
                           const float* __restrict__ W,
                           const float* __restrict__ bias,
                           const float* __restrict__ bn_gamma,
                           const float* __restrict__ bn_beta,
                           const float* __restrict__ bn_mean,
                           const float* __restrict__ bn_var,
                           float* __restrict__ out) {
  __shared__ float wl[C_ * D_];   // W[:,h,:] 16 KB
  int blk = blockIdx.x;
  int tcb = blk & 7;
  int h = (blk >> 3) & 3;
  int b = blk >> 5;
  int tid = threadIdx.x;
  int t = tcb * 64 + (tid & 63);
  int d0 = (tid >> 6) * 8;
  for (int i = tid; i < C_ * D_; i += 256) {
    int c = i >> 5, d = i & 31;
    wl[i] = W[((size_t)c * H_ + h) * D_ + d];
  }
  __syncthreads();
  float acc[8] = {0.f, 0.f, 0.f, 0.f, 0.f, 0.f, 0.f, 0.f};
  const float* yp = y_ws + ((size_t)b * H_ + h) * C_ * T_ + t;
  for (int c = 0; c < C_; ++c) {
    float yv = yp[(size_t)c * T_];
    const float4 w0 = *reinterpret_cast<const float4*>(&wl[c * D_ + d0]);
    const float4 w1 = *reinterpret_cast<const float4*>(&wl[c * D_ + d0 + 4]);
    acc[0] = fmaf(yv, w0.x, acc[0]); acc[1] = fmaf(yv, w0.y, acc[1]);
    acc[2] = fmaf(yv, w0.z, acc[2]); acc[3] = fmaf(yv, w0.w, acc[3]);
    acc[4] = fmaf(yv, w1.x, acc[4]); acc[5] = fmaf(yv, w1.y, acc[5]);
    acc[6] = fmaf(yv, w1.z, acc[6]); acc[7] = fmaf(yv, w1.w, acc[7]);
  }
#pragma unroll
  for (int k = 0; k < 8; ++k) {
    int oc = h * D_ + d0 + k;
    float scale = bn_gamma[oc] * rsqrtf(bn_var[oc] + BN_EPS);
    float shift = bn_beta[oc] - bn_mean[oc] * scale;
    out[((size_t)b * OUT_ + oc) * T_ + t] = (acc[k] + bias[oc]) * scale + shift;
  }
}

extern "C" void kernel_launch(void* const* d_in, const int* in_sizes, int n_in,
                              void* d_out, int out_size, void* d_ws, size_t ws_size,
                              hipStream_t stream) {
  const float* x        = (const float*)d_in[0];
  const float* W        = (const float*)d_in[1];
  const float* att_src  = (const float*)d_in[2];
  const float* att_dst  = (const float*)d_in[3];
  const float* bias     = (const float*)d_in[4];
  const float* bn_gamma = (const float*)d_in[5];
  const float* bn_beta  = (const float*)d_in[6];
  const float* bn_mean  = (const float*)d_in[7];
  const float* bn_var   = (const float*)d_in[8];
  const int* edge_index = (const int*)d_in[9];
  float* out = (float*)d_out;

  char* ws = (char*)d_ws;
  float* wa    = (float*)ws;                 // 1 KB
  int* csr_off = (int*)(ws + 4096);
  int* csr_src = (int*)(ws + 4608);
  float* a_ws  = (float*)(ws + 8192);        // 8 MB  [b][n][j][t]
  float* y_ws  = a_ws;                       // 8 MB  [b][h][c][t] (aliases a, dead after B1)
  float* w_ws  = (float*)(ws + 8192 + (size_t)8 * 1024 * 1024);  // 32 MB [b][n][t][h]

  setup_kernel<<<1, 256, 0, stream>>>(W, att_src, att_dst, edge_index,
                                      wa, csr_off, csr_src);
  proj_kernel<<<B_ * N_ * (T_ / 256), 256, 0, stream>>>(x, wa, a_ws);
  weights_kernel<<<B_ * (T_ / 16), 256, 0, stream>>>(a_ws, csr_off, csr_src, w_ws);
  agg_kernel<<<1024, 256, 0, stream>>>(x, w_ws, y_ws);
  out_kernel<<<B_ * H_ * (T_ / 64), 256, 0, stream>>>(y_ws, W, bias, bn_gamma,
                                                      bn_beta, bn_mean, bn_var, out);
}

// Round 3
// 103.890 us; speedup vs baseline: 1.5075x; 1.1102x over previous
//
#include <hip/hip_runtime.h>
#include <math.h>

#define B_ 8
#define C_ 128
#define N_ 64
#define T_ 512
#define H_ 4
#define D_ 32
#define OUT_ 128
#define E_ 256
#define EP_ 320   // E + N self-loops
#define NEG_SLOPE 0.2f
#define BN_EPS 1e-5f

// ---- setup: wa[c][8] = W·att, edge lists, in-CSR (by dst) and out-CSR (by src)
__global__ void setup_kernel(const float* __restrict__ W,
                             const float* __restrict__ att_src,
                             const float* __restrict__ att_dst,
                             const int* __restrict__ edge_index,
                             float* __restrict__ wa,
                             int* __restrict__ esrc_g, int* __restrict__ edst_g,
                             int* __restrict__ iOff_g, int* __restrict__ iEid_g,
                             int* __restrict__ oOff_g, int* __restrict__ oEid_g) {
  __shared__ int icnt[N_], ibase[N_ + 1], ifill[N_];
  __shared__ int ocnt[N_], obase[N_ + 1], ofill[N_];
  __shared__ int esrc[EP_], edst[EP_];
  int tid = threadIdx.x;

  for (int idx = tid; idx < C_ * 8; idx += blockDim.x) {
    int c = idx >> 3, j = idx & 7, h = j & 3;
    const float* att = (j < 4) ? att_src : att_dst;
    float s = 0.f;
    for (int d = 0; d < D_; ++d)
      s += W[(c * H_ + h) * D_ + d] * att[h * D_ + d];
    wa[idx] = s;
  }
  if (tid < N_) { icnt[tid] = 0; ifill[tid] = 0; ocnt[tid] = 0; ofill[tid] = 0; }
  __syncthreads();
  for (int e = tid; e < EP_; e += blockDim.x) {
    int s, d;
    if (e < E_) { s = edge_index[e]; d = edge_index[E_ + e]; }
    else        { s = e - E_;        d = e - E_; }
    esrc[e] = s; edst[e] = d;
    atomicAdd(&icnt[d], 1);
    atomicAdd(&ocnt[s], 1);
  }
  __syncthreads();
  if (tid == 0) {
    int ai = 0, ao = 0;
    for (int n = 0; n < N_; ++n) {
      ibase[n] = ai; ai += icnt[n];
      obase[n] = ao; ao += ocnt[n];
    }
    ibase[N_] = ai; obase[N_] = ao;
  }
  __syncthreads();
  if (tid <= N_) { iOff_g[tid] = ibase[tid]; oOff_g[tid] = obase[tid]; }
  for (int e = tid; e < EP_; e += blockDim.x) {
    esrc_g[e] = esrc[e]; edst_g[e] = edst[e];
    int d = edst[e];
    int pi = ibase[d] + atomicAdd(&ifill[d], 1);
    iEid_g[pi] = e;
    int s = esrc[e];
    int po = obase[s] + atomicAdd(&ofill[s], 1);
    oEid_g[po] = e;
  }
}

// ---- kernel A: a[b][n][j][t] = sum_c x[b][c][n][t] * wa[c][j] ------------------
// grid = B*N*(T/256) = 1024, block = 256, lanes over t -> coalesced x reads
__global__ void proj_kernel(const float* __restrict__ x,
                            const float* __restrict__ wa,
                            float* __restrict__ a_ws) {
  __shared__ float wal[C_ * 8];
  int tid = threadIdx.x;
  for (int i = tid; i < C_ * 8; i += 256) wal[i] = wa[i];
  __syncthreads();
  int blk = blockIdx.x;
  int tb = blk & 1;
  int n  = (blk >> 1) & (N_ - 1);
  int b  = blk >> 7;
  int t = tb * 256 + tid;
  const float* xp = x + ((size_t)(b * C_) * N_ + n) * T_ + t;
  float acc[8] = {0,0,0,0,0,0,0,0};
#pragma unroll 4
  for (int c = 0; c < C_; ++c) {
    float v = xp[(size_t)c * (N_ * T_)];
    const float* w8 = &wal[c * 8];
#pragma unroll
    for (int j = 0; j < 8; ++j) acc[j] = fmaf(v, w8[j], acc[j]);
  }
  float* ap = a_ws + (((size_t)b * N_ + n) * 8) * T_ + t;
#pragma unroll
  for (int j = 0; j < 8; ++j) ap[(size_t)j * T_] = acc[j];
}

// ---- kernel B1: segment softmax -> w[b][n][t][h], atomic-free ------------------
// grid = B*(T/16) = 256, block = 256 (1 block/CU; LDS ~120 KB)
__global__ __launch_bounds__(256, 1)
void weights_kernel(const float* __restrict__ a_ws,
                    const int* __restrict__ esrc_g, const int* __restrict__ edst_g,
                    const int* __restrict__ iOff_g, const int* __restrict__ iEid_g,
                    const int* __restrict__ oOff_g, const int* __restrict__ oEid_g,
                    float* __restrict__ w_ws) {
  __shared__ float a_l[8][64][16];    // [j][n][t]  32 KB
  __shared__ float4 sc[EP_][16];      // scores -> alpha, 80 KB
  __shared__ int eS[EP_], eD[EP_];
  __shared__ int iOff[N_ + 1], iEid[EP_], oOff[N_ + 1], oEid[EP_];
  int tid = threadIdx.x;
  int b  = blockIdx.x >> 5;
  int t0 = (blockIdx.x & 31) * 16;

  for (int i = tid; i < EP_; i += 256) {
    eS[i] = esrc_g[i]; eD[i] = edst_g[i];
    iEid[i] = iEid_g[i]; oEid[i] = oEid_g[i];
  }
  if (tid <= N_) { iOff[tid] = iOff_g[tid]; oOff[tid] = oOff_g[tid]; }
  for (int r = tid; r < 512; r += 256) {       // 512 rows of 16 floats
    int n = r >> 3, j = r & 7;
    const float4* src = reinterpret_cast<const float4*>(
        a_ws + (((size_t)b * N_ + n) * 8 + j) * T_ + t0);
    float4* dst = reinterpret_cast<float4*>(&a_l[j][n][0]);
    dst[0] = src[0]; dst[1] = src[1]; dst[2] = src[2]; dst[3] = src[3];
  }
  __syncthreads();

  // phase A: per-edge scores, leaky-relu
  for (int idx = tid; idx < EP_ * 16; idx += 256) {
    int e = idx >> 4, t = idx & 15;
    int s = eS[e], d = eD[e];
    float4 v;
    v.x = a_l[0][s][t] + a_l[4][d][t];
    v.y = a_l[1][s][t] + a_l[5][d][t];
    v.z = a_l[2][s][t] + a_l[6][d][t];
    v.w = a_l[3][s][t] + a_l[7][d][t];
    v.x = v.x > 0.f ? v.x : NEG_SLOPE * v.x;
    v.y = v.y > 0.f ? v.y : NEG_SLOPE * v.y;
    v.z = v.z > 0.f ? v.z : NEG_SLOPE * v.z;
    v.w = v.w > 0.f ? v.w : NEG_SLOPE * v.w;
    sc[e][t] = v;
  }
  __syncthreads();

  // phase B: per (dst,t) softmax over in-edges; rescale in place (owner-writes)
  for (int idx = tid; idx < N_ * 16; idx += 256) {
    int nd = idx >> 4, t = idx & 15;
    int e0 = iOff[nd], e1 = iOff[nd + 1];
    float m0 = -1e30f, m1 = -1e30f, m2 = -1e30f, m3 = -1e30f;
    for (int e = e0; e < e1; ++e) {
      float4 v = sc[iEid[e]][t];
      m0 = fmaxf(m0, v.x); m1 = fmaxf(m1, v.y);
      m2 = fmaxf(m2, v.z); m3 = fmaxf(m3, v.w);
    }
    float d0 = 0.f, d1 = 0.f, d2 = 0.f, d3 = 0.f;
    for (int e = e0; e < e1; ++e) {
      float4 v = sc[iEid[e]][t];
      d0 += __expf(v.x - m0); d1 += __expf(v.y - m1);
      d2 += __expf(v.z - m2); d3 += __expf(v.w - m3);
    }
    float i0 = 1.f / (d0 * (float)N_);   // fold mean-over-nodes 1/N
    float i1 = 1.f / (d1 * (float)N_);
    float i2 = 1.f / (d2 * (float)N_);
    float i3 = 1.f / (d3 * (float)N_);
    for (int e = e0; e < e1; ++e) {
      int ee = iEid[e];
      float4 v = sc[ee][t];
      v.x = __expf(v.x - m0) * i0; v.y = __expf(v.y - m1) * i1;
      v.z = __expf(v.z - m2) * i2; v.w = __expf(v.w - m3) * i3;
      sc[ee][t] = v;
    }
  }
  __syncthreads();

  // phase C: gather alpha by src -> w[b][n][t][h]
  for (int idx = tid; idx < N_ * 16; idx += 256) {
    int s = idx >> 4, t = idx & 15;
    int e0 = oOff[s], e1 = oOff[s + 1];
    float4 acc = {0.f, 0.f, 0.f, 0.f};
    for (int e = e0; e < e1; ++e) {
      float4 v = sc[oEid[e]][t];
      acc.x += v.x; acc.y += v.y; acc.z += v.z; acc.w += v.w;
    }
    *reinterpret_cast<float4*>(
        w_ws + ((size_t)(b * N_ + s) * T_ + t0 + t) * 4) = acc;
  }
}

// ---- kernel B2: y[b][h][c][t] = sum_n w[b][n][t][h] * x[b][c][n][t] ------------
// grid = 1024: b = blk&7 pins batch -> XCD (w[b] 512 KB lives in that L2),
// c = blk>>3; block streams the contiguous 128 KB x[b][c] panel.
__global__ void agg_kernel(const float* __restrict__ x,
                           const float* __restrict__ w_ws,
                           float* __restrict__ y_ws) {
  int blk = blockIdx.x;
  int b = blk & 7;
  int c = blk >> 3;
  int tid = threadIdx.x;
  const float* xp = x + ((size_t)(b * C_ + c) * N_) * T_ + tid;
  const float4* wp = reinterpret_cast<const float4*>(w_ws)
                   + (size_t)b * N_ * T_ + tid;
  float a00 = 0.f, a01 = 0.f, a02 = 0.f, a03 = 0.f;
  float a10 = 0.f, a11 = 0.f, a12 = 0.f, a13 = 0.f;
#pragma unroll 4
  for (int n = 0; n < N_; ++n) {
    float x0 = xp[n * T_];
    float x1 = xp[n * T_ + 256];
    float4 w0 = wp[n * T_];
    float4 w1 = wp[n * T_ + 256];
    a00 = fmaf(x0, w0.x, a00); a01 = fmaf(x0, w0.y, a01);
    a02 = fmaf(x0, w0.z, a02); a03 = fmaf(x0, w0.w, a03);
    a10 = fmaf(x1, w1.x, a10); a11 = fmaf(x1, w1.y, a11);
    a12 = fmaf(x1, w1.z, a12); a13 = fmaf(x1, w1.w, a13);
  }
  size_t yb = ((size_t)b * H_ * C_ + c) * T_ + tid;
  const size_t hs = (size_t)C_ * T_;
  y_ws[yb]               = a00; y_ws[yb + hs]       = a01;
  y_ws[yb + 2 * hs]      = a02; y_ws[yb + 3 * hs]   = a03;
  y_ws[yb + 256]          = a10; y_ws[yb + hs + 256]     = a11;
  y_ws[yb + 2 * hs + 256] = a12; y_ws[yb + 3 * hs + 256] = a13;
}

// ---- kernel B3: out = BN(y·W + bias); b in low bits -> y[b] read from own XCD L2
__global__ void out_kernel(const float* __restrict__ y_ws,
                           const float* __restrict__ W,
                           const float* __restrict__ bias,
                           const float* __restrict__ bn_gamma,
                           const float* __restrict__ bn_beta,
                           const float* __restrict__ bn_mean,
                           const float* __restrict__ bn_var,
                           float* __restrict__ out) {
  __shared__ float wl[C_ * D_];   // W[:,h,:] 16 KB
  int blk = blockIdx.x;
  int b = blk & 7;
  int h = (blk >> 3) & 3;
  int tcb = blk >> 5;
  int tid = threadIdx.x;
  int t = tcb * 64 + (tid & 63);
  int d0 = (tid >> 6) * 8;
  for (int i = tid; i < C_ * D_; i += 256) {
    int c = i >> 5, d = i & 31;
    wl[i] = W[((size_t)c * H_ + h) * D_ + d];
  }
  __syncthreads();
  float acc[8] = {0.f, 0.f, 0.f, 0.f, 0.f, 0.f, 0.f, 0.f};
  const float* yp = y_ws + ((size_t)b * H_ + h) * C_ * T_ + t;
#pragma unroll 4
  for (int c = 0; c < C_; ++c) {
    float yv = yp[(size_t)c * T_];
    const float4 w0 = *reinterpret_cast<const float4*>(&wl[c * D_ + d0]);
    const float4 w1 = *reinterpret_cast<const float4*>(&wl[c * D_ + d0 + 4]);
    acc[0] = fmaf(yv, w0.x, acc[0]); acc[1] = fmaf(yv, w0.y, acc[1]);
    acc[2] = fmaf(yv, w0.z, acc[2]); acc[3] = fmaf(yv, w0.w, acc[3]);
    acc[4] = fmaf(yv, w1.x, acc[4]); acc[5] = fmaf(yv, w1.y, acc[5]);
    acc[6] = fmaf(yv, w1.z, acc[6]); acc[7] = fmaf(yv, w1.w, acc[7]);
  }
#pragma unroll
  for (int k = 0; k < 8; ++k) {
    int oc = h * D_ + d0 + k;
    float scale = bn_gamma[oc] * rsqrtf(bn_var[oc] + BN_EPS);
    float shift = bn_beta[oc] - bn_mean[oc] * scale;
    out[((size_t)b * OUT_ + oc) * T_ + t] = (acc[k] + bias[oc]) * scale + shift;
  }
}

extern "C" void kernel_launch(void* const* d_in, const int* in_sizes, int n_in,
                              void* d_out, int out_size, void* d_ws, size_t ws_size,
                              hipStream_t stream) {
  const float* x        = (const float*)d_in[0];
  const float* W        = (const float*)d_in[1];
  const float* att_src  = (const float*)d_in[2];
  const float* att_dst  = (const float*)d_in[3];
  const float* bias     = (const float*)d_in[4];
  const float* bn_gamma = (const float*)d_in[5];
  const float* bn_beta  = (const float*)d_in[6];
  const float* bn_mean  = (const float*)d_in[7];
  const float* bn_var   = (const float*)d_in[8];
  const int* edge_index = (const int*)d_in[9];
  float* out = (float*)d_out;

  char* ws = (char*)d_ws;
  float* wa    = (float*)ws;                  // 4 KB
  int* esrc_g  = (int*)(ws + 4096);           // 1.25 KB (pad to 2 KB)
  int* edst_g  = (int*)(ws + 6144);
  int* iOff_g  = (int*)(ws + 8192);
  int* iEid_g  = (int*)(ws + 8704);
  int* oOff_g  = (int*)(ws + 10752);
  int* oEid_g  = (int*)(ws + 11264);
  float* a_ws  = (float*)(ws + 16384);        // 8 MB  [b][n][j][t]
  float* y_ws  = a_ws;                        // 8 MB  [b][h][c][t] (aliases a)
  float* w_ws  = (float*)(ws + 16384 + (size_t)8 * 1024 * 1024);  // 4 MB [b][n][t][h]

  setup_kernel<<<1, 256, 0, stream>>>(W, att_src, att_dst, edge_index, wa,
                                      esrc_g, edst_g, iOff_g, iEid_g, oOff_g, oEid_g);
  proj_kernel<<<B_ * N_ * (T_ / 256), 256, 0, stream>>>(x, wa, a_ws);
  weights_kernel<<<B_ * (T_ / 16), 256, 0, stream>>>(a_ws, esrc_g, edst_g,
                                                     iOff_g, iEid_g, oOff_g, oEid_g,
                                                     w_ws);
  agg_kernel<<<1024, 256, 0, stream>>>(x, w_ws, y_ws);
  out_kernel<<<B_ * H_ * (T_ / 64), 256, 0, stream>>>(y_ws, W, bias, bn_gamma,
                                                      bn_beta, bn_mean, bn_var, out);
}

// Round 4
// 77.379 us; speedup vs baseline: 2.0240x; 1.3426x over previous
//
#include <hip/hip_runtime.h>
#include <math.h>

#define B_ 8
#define C_ 128
#define N_ 64
#define T_ 512
#define H_ 4
#define D_ 32
#define OUT_ 128
#define E_ 256
#define EP_ 320   // E + N self-loops
#define NEG_SLOPE 0.2f
#define BN_EPS 1e-5f
#define TC 16     // time steps per block

// ---- setup: wa[c][8] = W·att; in-list (src per in-edge, grouped by dst);
// ----        out-list (dst per out-edge, grouped by src)
__global__ void setup_kernel(const float* __restrict__ W,
                             const float* __restrict__ att_src,
                             const float* __restrict__ att_dst,
                             const int* __restrict__ edge_index,
                             float* __restrict__ wa,
                             int* __restrict__ iOff_g, int* __restrict__ iSrc_g,
                             int* __restrict__ oOff_g, int* __restrict__ oDst_g) {
  __shared__ int icnt[N_], ibase[N_ + 1], ifill[N_];
  __shared__ int ocnt[N_], obase[N_ + 1], ofill[N_];
  __shared__ int esrc[EP_], edst[EP_];
  int tid = threadIdx.x;

  for (int idx = tid; idx < C_ * 8; idx += blockDim.x) {
    int c = idx >> 3, j = idx & 7, h = j & 3;
    const float* att = (j < 4) ? att_src : att_dst;
    float s = 0.f;
    for (int d = 0; d < D_; ++d)
      s += W[(c * H_ + h) * D_ + d] * att[h * D_ + d];
    wa[idx] = s;
  }
  if (tid < N_) { icnt[tid] = 0; ifill[tid] = 0; ocnt[tid] = 0; ofill[tid] = 0; }
  __syncthreads();
  for (int e = tid; e < EP_; e += blockDim.x) {
    int s, d;
    if (e < E_) { s = edge_index[e]; d = edge_index[E_ + e]; }
    else        { s = e - E_;        d = e - E_; }
    esrc[e] = s; edst[e] = d;
    atomicAdd(&icnt[d], 1);
    atomicAdd(&ocnt[s], 1);
  }
  __syncthreads();
  if (tid == 0) {
    int ai = 0, ao = 0;
    for (int n = 0; n < N_; ++n) {
      ibase[n] = ai; ai += icnt[n];
      obase[n] = ao; ao += ocnt[n];
    }
    ibase[N_] = ai; obase[N_] = ao;
  }
  __syncthreads();
  if (tid <= N_) { iOff_g[tid] = ibase[tid]; oOff_g[tid] = obase[tid]; }
  for (int e = tid; e < EP_; e += blockDim.x) {
    int s = esrc[e], d = edst[e];
    int pi = ibase[d] + atomicAdd(&ifill[d], 1);
    iSrc_g[pi] = s;
    int po = obase[s] + atomicAdd(&ofill[s], 1);
    oDst_g[po] = d;
  }
}

// ---- megakernel: one block per (b, 16-t chunk). grid = 256 = 1 block/CU.
// pass1: stream x -> a (regs -> LDS); softmax in LDS; pass2: re-read x (L2/L3)
// -> y regs -> LDS; pass3: y·W + bias + BN -> out. Zero workspace traffic.
__global__ __launch_bounds__(256, 1)
void mega_kernel(const float* __restrict__ x,
                 const float* __restrict__ wa_g,
                 const float* __restrict__ W,
                 const int* __restrict__ iOff_g, const int* __restrict__ iSrc_g,
                 const int* __restrict__ oOff_g, const int* __restrict__ oDst_g,
                 const float* __restrict__ bias,
                 const float* __restrict__ bn_gamma,
                 const float* __restrict__ bn_beta,
                 const float* __restrict__ bn_mean,
                 const float* __restrict__ bn_var,
                 float* __restrict__ out) {
  __shared__ float a_l[8 * 64 * 20];     // [j][n][16+4pad]; later overlaid y[4][128][17]
  __shared__ float m_l[64 * 16 * 4];     // [nd][t][h]
  __shared__ float inv_l[64 * 16 * 4];   // [nd][t][h]  (1/(den*N))
  __shared__ float w_l[64 * 4 * 16];     // [n][h][t]
  __shared__ float wal[C_ * 8];
  __shared__ int iOff[N_ + 1], oOff[N_ + 1];
  __shared__ int iSrc[EP_], oDst[EP_];

  const int tid = threadIdx.x;
  // block -> (b, tc): t-half pairs (tc=2k, 2k+1) land on the same XCD so the
  // 128-B x lines they share are fetched from HBM once.
  const int xcd = blockIdx.x & 7;
  const int jj  = blockIdx.x >> 3;           // 0..31
  const int pair = xcd * 16 + (jj & 15);     // 0..127 = (b, tc-pair)
  const int parity = jj >> 4;                // 0..1
  const int b  = pair >> 4;
  const int tc = ((pair & 15) << 1) | parity;
  const int t0 = tc * TC;

  for (int i = tid; i < EP_; i += 256) { iSrc[i] = iSrc_g[i]; oDst[i] = oDst_g[i]; }
  if (tid <= N_) { iOff[tid] = iOff_g[tid]; oOff[tid] = oOff_g[tid]; }
  for (int i = tid; i < C_ * 8; i += 256) wal[i] = wa_g[i];
  __syncthreads();

  // ---------------- pass 1: a[j][n][t] = sum_c x[b][c][n][t]*wa[c][j] ----------
  {
    const int n1 = tid >> 2, q = tid & 3;     // thread owns (n1, t = q*4..q*4+3)
    const float* xp = x + ((size_t)(b * C_) * N_ + n1) * T_ + t0 + q * 4;
    float acc[8][4];
#pragma unroll
    for (int j = 0; j < 8; ++j)
#pragma unroll
      for (int tt = 0; tt < 4; ++tt) acc[j][tt] = 0.f;
#pragma unroll 4
    for (int c = 0; c < C_; ++c) {
      float4 xv = *reinterpret_cast<const float4*>(xp + (size_t)c * (N_ * T_));
      float xq[4] = {xv.x, xv.y, xv.z, xv.w};
#pragma unroll
      for (int j = 0; j < 8; ++j) {
        float wj = wal[c * 8 + j];
#pragma unroll
        for (int tt = 0; tt < 4; ++tt) acc[j][tt] = fmaf(xq[tt], wj, acc[j][tt]);
      }
    }
#pragma unroll
    for (int j = 0; j < 8; ++j) {
      float4 v; v.x = acc[j][0]; v.y = acc[j][1]; v.z = acc[j][2]; v.w = acc[j][3];
      *reinterpret_cast<float4*>(&a_l[j * 1280 + n1 * 20 + q * 4]) = v;
    }
  }
  __syncthreads();

  // ---------------- softmax phase B: per (dst,t) max & denom -------------------
  {
    const int t = tid & 15, grp = tid >> 4;   // 16 t x 16 groups
#pragma unroll
    for (int rep = 0; rep < 4; ++rep) {
      int nd = grp + rep * 16;
      int e0 = iOff[nd], e1 = iOff[nd + 1];
      float ad0 = a_l[4 * 1280 + nd * 20 + t];
      float ad1 = a_l[5 * 1280 + nd * 20 + t];
      float ad2 = a_l[6 * 1280 + nd * 20 + t];
      float ad3 = a_l[7 * 1280 + nd * 20 + t];
      float m0 = -1e30f, m1 = -1e30f, m2 = -1e30f, m3 = -1e30f;
      for (int e = e0; e < e1; ++e) {
        int s = iSrc[e];
        float v0 = a_l[0 * 1280 + s * 20 + t] + ad0; v0 = v0 > 0.f ? v0 : NEG_SLOPE * v0;
        float v1 = a_l[1 * 1280 + s * 20 + t] + ad1; v1 = v1 > 0.f ? v1 : NEG_SLOPE * v1;
        float v2 = a_l[2 * 1280 + s * 20 + t] + ad2; v2 = v2 > 0.f ? v2 : NEG_SLOPE * v2;
        float v3 = a_l[3 * 1280 + s * 20 + t] + ad3; v3 = v3 > 0.f ? v3 : NEG_SLOPE * v3;
        m0 = fmaxf(m0, v0); m1 = fmaxf(m1, v1);
        m2 = fmaxf(m2, v2); m3 = fmaxf(m3, v3);
      }
      float d0 = 0.f, d1 = 0.f, d2 = 0.f, d3 = 0.f;
      for (int e = e0; e < e1; ++e) {
        int s = iSrc[e];
        float v0 = a_l[0 * 1280 + s * 20 + t] + ad0; v0 = v0 > 0.f ? v0 : NEG_SLOPE * v0;
        float v1 = a_l[1 * 1280 + s * 20 + t] + ad1; v1 = v1 > 0.f ? v1 : NEG_SLOPE * v1;
        float v2 = a_l[2 * 1280 + s * 20 + t] + ad2; v2 = v2 > 0.f ? v2 : NEG_SLOPE * v2;
        float v3 = a_l[3 * 1280 + s * 20 + t] + ad3; v3 = v3 > 0.f ? v3 : NEG_SLOPE * v3;
        d0 += __expf(v0 - m0); d1 += __expf(v1 - m1);
        d2 += __expf(v2 - m2); d3 += __expf(v3 - m3);
      }
      float4 mv; mv.x = m0; mv.y = m1; mv.z = m2; mv.w = m3;
      float4 iv; iv.x = 1.f / (d0 * (float)N_); iv.y = 1.f / (d1 * (float)N_);
      iv.z = 1.f / (d2 * (float)N_); iv.w = 1.f / (d3 * (float)N_);
      *reinterpret_cast<float4*>(&m_l[(nd * 16 + t) * 4]) = mv;
      *reinterpret_cast<float4*>(&inv_l[(nd * 16 + t) * 4]) = iv;
    }
  }
  __syncthreads();

  // ---------------- softmax phase C: per (src,t) gather -> w[n][h][t] ----------
  {
    const int t = tid & 15, grp = tid >> 4;
#pragma unroll
    for (int rep = 0; rep < 4; ++rep) {
      int src = grp + rep * 16;
      int e0 = oOff[src], e1 = oOff[src + 1];
      float as0 = a_l[0 * 1280 + src * 20 + t];
      float as1 = a_l[1 * 1280 + src * 20 + t];
      float as2 = a_l[2 * 1280 + src * 20 + t];
      float as3 = a_l[3 * 1280 + src * 20 + t];
      float w0 = 0.f, w1 = 0.f, w2 = 0.f, w3 = 0.f;
      for (int e = e0; e < e1; ++e) {
        int d = oDst[e];
        float4 mv = *reinterpret_cast<const float4*>(&m_l[(d * 16 + t) * 4]);
        float4 iv = *reinterpret_cast<const float4*>(&inv_l[(d * 16 + t) * 4]);
        float v0 = as0 + a_l[4 * 1280 + d * 20 + t]; v0 = v0 > 0.f ? v0 : NEG_SLOPE * v0;
        float v1 = as1 + a_l[5 * 1280 + d * 20 + t]; v1 = v1 > 0.f ? v1 : NEG_SLOPE * v1;
        float v2 = as2 + a_l[6 * 1280 + d * 20 + t]; v2 = v2 > 0.f ? v2 : NEG_SLOPE * v2;
        float v3 = as3 + a_l[7 * 1280 + d * 20 + t]; v3 = v3 > 0.f ? v3 : NEG_SLOPE * v3;
        w0 += __expf(v0 - mv.x) * iv.x;
        w1 += __expf(v1 - mv.y) * iv.y;
        w2 += __expf(v2 - mv.z) * iv.z;
        w3 += __expf(v3 - mv.w) * iv.w;
      }
      w_l[src * 64 +  0 + t] = w0;
      w_l[src * 64 + 16 + t] = w1;
      w_l[src * 64 + 32 + t] = w2;
      w_l[src * 64 + 48 + t] = w3;
    }
  }
  __syncthreads();

  // ---------------- pass 2: y[h][c][t] = sum_n w[n][h][t] * x[b][c][n][t] ------
  {
    const int t2 = tid & 15, cl = tid >> 4;   // c = cg*16 + cl
    const float* xb = x + ((size_t)(b * C_) + cl) * N_ * T_ + t0 + t2;
    float yr[8][4];
#pragma unroll
    for (int cg = 0; cg < 8; ++cg)
#pragma unroll
      for (int h = 0; h < 4; ++h) yr[cg][h] = 0.f;
#pragma unroll 2
    for (int n = 0; n < N_; ++n) {
      float w0 = w_l[n * 64 +  0 + t2];
      float w1 = w_l[n * 64 + 16 + t2];
      float w2 = w_l[n * 64 + 32 + t2];
      float w3 = w_l[n * 64 + 48 + t2];
#pragma unroll
      for (int cg = 0; cg < 8; ++cg) {
        float xv = xb[(size_t)cg * 16 * N_ * T_ + (size_t)n * T_];
        yr[cg][0] = fmaf(xv, w0, yr[cg][0]);
        yr[cg][1] = fmaf(xv, w1, yr[cg][1]);
        yr[cg][2] = fmaf(xv, w2, yr[cg][2]);
        yr[cg][3] = fmaf(xv, w3, yr[cg][3]);
      }
    }
    float* y_l = a_l;                          // overlay (a dead after phase C)
#pragma unroll
    for (int cg = 0; cg < 8; ++cg)
#pragma unroll
      for (int h = 0; h < 4; ++h)
        y_l[h * 2176 + (cg * 16 + cl) * 17 + t2] = yr[cg][h];
  }
  __syncthreads();

  // ---------------- pass 3: out[oc][t] = BN(sum_c y[h][c][t]*W[c][h][d] + bias)
  {
    const int t3 = tid & 15, g = tid >> 4;     // g 0..15
    const int h = g >> 2, d0 = (g & 3) * 8;    // 8 d's per thread
    const float* y_l = a_l;
    float acc[8];
#pragma unroll
    for (int k = 0; k < 8; ++k) acc[k] = 0.f;
#pragma unroll 4
    for (int c = 0; c < C_; ++c) {
      float yv = y_l[h * 2176 + c * 17 + t3];
      const float4 wv0 = *reinterpret_cast<const float4*>(
          &W[((size_t)c * H_ + h) * D_ + d0]);
      const float4 wv1 = *reinterpret_cast<const float4*>(
          &W[((size_t)c * H_ + h) * D_ + d0 + 4]);
      acc[0] = fmaf(yv, wv0.x, acc[0]); acc[1] = fmaf(yv, wv0.y, acc[1]);
      acc[2] = fmaf(yv, wv0.z, acc[2]); acc[3] = fmaf(yv, wv0.w, acc[3]);
      acc[4] = fmaf(yv, wv1.x, acc[4]); acc[5] = fmaf(yv, wv1.y, acc[5]);
      acc[6] = fmaf(yv, wv1.z, acc[6]); acc[7] = fmaf(yv, wv1.w, acc[7]);
    }
#pragma unroll
    for (int k = 0; k < 8; ++k) {
      int oc = h * D_ + d0 + k;
      float scale = bn_gamma[oc] * rsqrtf(bn_var[oc] + BN_EPS);
      float shift = bn_beta[oc] - bn_mean[oc] * scale;
      out[((size_t)b * OUT_ + oc) * T_ + t0 + t3] =
          (acc[k] + bias[oc]) * scale + shift;
    }
  }
}

extern "C" void kernel_launch(void* const* d_in, const int* in_sizes, int n_in,
                              void* d_out, int out_size, void* d_ws, size_t ws_size,
                              hipStream_t stream) {
  const float* x        = (const float*)d_in[0];
  const float* W        = (const float*)d_in[1];
  const float* att_src  = (const float*)d_in[2];
  const float* att_dst  = (const float*)d_in[3];
  const float* bias     = (const float*)d_in[4];
  const float* bn_gamma = (const float*)d_in[5];
  const float* bn_beta  = (const float*)d_in[6];
  const float* bn_mean  = (const float*)d_in[7];
  const float* bn_var   = (const float*)d_in[8];
  const int* edge_index = (const int*)d_in[9];
  float* out = (float*)d_out;

  char* ws = (char*)d_ws;
  float* wa   = (float*)ws;            // 4 KB
  int* iOff_g = (int*)(ws + 4096);     // 65 ints
  int* iSrc_g = (int*)(ws + 4608);     // 320 ints
  int* oOff_g = (int*)(ws + 6144);     // 65 ints
  int* oDst_g = (int*)(ws + 6656);     // 320 ints

  setup_kernel<<<1, 256, 0, stream>>>(W, att_src, att_dst, edge_index, wa,
                                      iOff_g, iSrc_g, oOff_g, oDst_g);
  mega_kernel<<<256, 256, 0, stream>>>(x, wa, W, iOff_g, iSrc_g, oOff_g, oDst_g,
                                       bias, bn_gamma, bn_beta, bn_mean, bn_var,
                                       out);
}